// Round 8
// baseline (1130.179 us; speedup 1.0000x reference)
//
#include <hip/hip_runtime.h>

#define NBLK 512
#define WSTRIDE 264               // bf16 elems per weight-col row (528B, conflict-free b128)
#define WPLANE (64 * WSTRIDE)     // one gate's 64 cols
#define BH 33554432               // B*H

typedef __attribute__((ext_vector_type(8))) short bf16x8;
typedef __attribute__((ext_vector_type(4))) float f32x4;
typedef __attribute__((ext_vector_type(8))) unsigned short u16x8;

__device__ __forceinline__ unsigned short f2bf(float f) {
  unsigned int u = __float_as_uint(f);
  u += 0x7fffu + ((u >> 16) & 1u);  // round-to-nearest-even
  return (unsigned short)(u >> 16);
}

__device__ __forceinline__ float fexp(float x) { return __builtin_amdgcn_exp2f(x * 1.44269504f); }
__device__ __forceinline__ float sigm(float x) { return __builtin_amdgcn_rcpf(1.f + fexp(-x)); }
__device__ __forceinline__ float ftanh(float x) { return 1.f - 2.f * __builtin_amdgcn_rcpf(1.f + fexp(2.f * x)); }

// Inverted data flow: weights (4 gates x 64 cols x 256 K, bf16) live in LDS,
// read-only after init -> NO barriers in the main loop. Each wave streams its
// own 16-row tiles: X/H loaded straight to regs, cvt'd in-reg to MFMA B-frags.
// MFMA operands swapped (weights = A): D[wcol=lkq*4+j][brow=lrow] (r7-verified).
__global__ __launch_bounds__(512, 2) void lstm_fused(
    const float* __restrict__ X, const float* __restrict__ H0, const float* __restrict__ C0,
    const float* __restrict__ Wii, const float* __restrict__ Whi,
    const float* __restrict__ Wif, const float* __restrict__ Whf,
    const float* __restrict__ Wio, const float* __restrict__ Who,
    const float* __restrict__ Wig, const float* __restrict__ Whg,
    float* __restrict__ Out) {
  __shared__ __align__(16) unsigned short Wlds[4 * WPLANE];  // 135168 B

  const int tid = threadIdx.x;
  const int wid = tid >> 6;
  const int lane = tid & 63;
  const int lrow = lane & 15;      // batch row within the wave's 16-row tile
  const int lkq = lane >> 4;       // k-quarter / output col-quarter

  // XCD pairing: {bid, bid+8} share bid&7 (same XCD), cover the two col-halves
  // of the same 1024-row group -> duplicated X/H reads hit that XCD's L2.
  const int bid = blockIdx.x;
  const int xcd = bid & 7;
  const int ch = (bid >> 3) & 1;   // col half
  const int p = bid >> 4;          // 0..31
  const int rowg = p + 32 * xcd;   // row group [0,256)
  const int row_base = rowg * 1024;
  const int col0 = ch * 64;

  const float* Wxp[4] = {Wii, Wif, Wio, Wig};
  const float* Whp[4] = {Whi, Whf, Who, Whg};

  // per-wave streaming state (all statically indexed)
  float4 ax[16];                   // staged X/H fp32 for next tile
  bf16x8 bf[8];                    // current tile's B-frags
  f32x4 cvA[4], cvB[4];            // C_prev ping-pong
  f32x4 acc[4][4];                 // [col-tile][gate]

#define ISSUE_A(ROW0) do {                                                \
    const float* xb_ = X + (size_t)((ROW0) + lrow) * 128 + lkq * 8;       \
    const float* hb_ = H0 + (size_t)((ROW0) + lrow) * 128 + lkq * 8;      \
    _Pragma("unroll")                                                     \
    for (int kk_ = 0; kk_ < 4; ++kk_) {                                   \
      ax[2 * kk_]     = *(const float4*)(xb_ + kk_ * 32);                 \
      ax[2 * kk_ + 1] = *(const float4*)(xb_ + kk_ * 32 + 4);             \
      ax[8 + 2 * kk_]     = *(const float4*)(hb_ + kk_ * 32);             \
      ax[8 + 2 * kk_ + 1] = *(const float4*)(hb_ + kk_ * 32 + 4);         \
    }                                                                     \
  } while (0)

#define ISSUE_C(ROW0, CV) do {                                            \
    _Pragma("unroll")                                                     \
    for (int ct_ = 0; ct_ < 4; ++ct_)                                     \
      CV[ct_] = *(const f32x4*)(C0 + (size_t)((ROW0) + lrow) * 128        \
                                + col0 + ct_ * 16 + lkq * 4);             \
  } while (0)

#define TILE(T, CVR, CVW) do {                                            \
    const int row0_ = row_base + (T) * 128 + wid * 16;                    \
    /* cvt staged fp32 -> bf16 B-frags (in-reg, no LDS) */                \
    _Pragma("unroll")                                                     \
    for (int kk_ = 0; kk_ < 8; ++kk_) {                                   \
      bf16x8 t_;                                                          \
      t_[0] = (short)f2bf(ax[2 * kk_].x); t_[1] = (short)f2bf(ax[2 * kk_].y); \
      t_[2] = (short)f2bf(ax[2 * kk_].z); t_[3] = (short)f2bf(ax[2 * kk_].w); \
      t_[4] = (short)f2bf(ax[2 * kk_ + 1].x); t_[5] = (short)f2bf(ax[2 * kk_ + 1].y); \
      t_[6] = (short)f2bf(ax[2 * kk_ + 1].z); t_[7] = (short)f2bf(ax[2 * kk_ + 1].w); \
      bf[kk_] = t_;                                                       \
    }                                                                     \
    /* prefetch next tile (A first = oldest; its wait leaves C in flight) */ \
    if ((T) + 1 < 8) {                                                    \
      ISSUE_A(row0_ + 128);                                               \
      ISSUE_C(row0_ + 128, CVW);                                          \
    }                                                                     \
    /* 128 MFMA: weights from LDS (conflict-free b128), no barrier */     \
    _Pragma("unroll")                                                     \
    for (int ct_ = 0; ct_ < 4; ++ct_)                                     \
      _Pragma("unroll")                                                   \
      for (int g_ = 0; g_ < 4; ++g_)                                      \
        acc[ct_][g_] = (f32x4){0.f, 0.f, 0.f, 0.f};                       \
    _Pragma("unroll")                                                     \
    for (int ct_ = 0; ct_ < 4; ++ct_) {                                   \
      _Pragma("unroll")                                                   \
      for (int kk_ = 0; kk_ < 8; ++kk_) {                                 \
        _Pragma("unroll")                                                 \
        for (int g_ = 0; g_ < 4; ++g_) {                                  \
          bf16x8 w_ = *(const bf16x8*)&Wlds[g_ * WPLANE                   \
              + (ct_ * 16 + lrow) * WSTRIDE + kk_ * 32 + lkq * 8];        \
          acc[ct_][g_] = __builtin_amdgcn_mfma_f32_16x16x32_bf16(         \
              w_, bf[kk_], acc[ct_][g_], 0, 0, 0);                        \
        }                                                                 \
      }                                                                   \
    }                                                                     \
    /* fused epilogue + plain dwordx4 stores */                           \
    _Pragma("unroll")                                                     \
    for (int ct_ = 0; ct_ < 4; ++ct_) {                                   \
      f32x4 hv_, cf_;                                                     \
      _Pragma("unroll")                                                   \
      for (int j_ = 0; j_ < 4; ++j_) {                                    \
        const float itv = sigm(acc[ct_][0][j_]);                          \
        const float ftv = sigm(acc[ct_][1][j_]);                          \
        const float otv = sigm(acc[ct_][2][j_]);                          \
        const float gtv = ftanh(acc[ct_][3][j_]);                         \
        const float ctv = ftv * (CVR)[ct_][j_] + itv * gtv;               \
        cf_[j_] = ctv;                                                    \
        hv_[j_] = otv * ftanh(ctv);                                       \
      }                                                                   \
      const size_t ob_ = (size_t)(row0_ + lrow) * 128 + col0 + ct_ * 16 + lkq * 4; \
      *(f32x4*)(Out + ob_) = hv_;                                         \
      *(f32x4*)(Out + BH + ob_) = cf_;                                    \
    }                                                                     \
  } while (0)

  // ---- prologue: issue wave's first tile loads before touching weights ----
  ISSUE_A(row_base + wid * 16);
  ISSUE_C(row_base + wid * 16, cvA);

  // ---- weight init: 4 gates x 64 cols x 256 K fp32 -> bf16 LDS (once) ----
  {
    const int c_ = tid >> 3;       // weight col 0..63
    const int q_ = tid & 7;        // 32-K chunk
#pragma unroll
    for (int g_ = 0; g_ < 4; ++g_) {
      const float* src = (q_ < 4) ? (Wxp[g_] + (size_t)(col0 + c_) * 128 + q_ * 32)
                                  : (Whp[g_] + (size_t)(col0 + c_) * 128 + (q_ - 4) * 32);
#pragma unroll
      for (int m_ = 0; m_ < 4; ++m_) {
        float4 lo = ((const float4*)src)[2 * m_];
        float4 hi = ((const float4*)src)[2 * m_ + 1];
        u16x8 t_;
        t_[0] = f2bf(lo.x); t_[1] = f2bf(lo.y); t_[2] = f2bf(lo.z); t_[3] = f2bf(lo.w);
        t_[4] = f2bf(hi.x); t_[5] = f2bf(hi.y); t_[6] = f2bf(hi.z); t_[7] = f2bf(hi.w);
        *(u16x8*)&Wlds[g_ * WPLANE + c_ * WSTRIDE + q_ * 32 + m_ * 8] = t_;
      }
    }
  }
  __syncthreads();  // the ONLY barrier; weights read-only afterwards

  // ---- 8 tiles per wave, unroll-by-2 for C ping-pong ----
  for (int t = 0; t < 8; t += 2) {
    TILE(t, cvA, cvB);
    TILE(t + 1, cvB, cvA);
  }

#undef ISSUE_A
#undef ISSUE_C
#undef TILE
}

extern "C" void kernel_launch(void* const* d_in, const int* in_sizes, int n_in,
                              void* d_out, int out_size, void* d_ws, size_t ws_size,
                              hipStream_t stream) {
  (void)in_sizes; (void)n_in; (void)out_size; (void)d_ws; (void)ws_size;
  lstm_fused<<<NBLK, 512, 0, stream>>>(
      (const float*)d_in[0], (const float*)d_in[1], (const float*)d_in[2],
      (const float*)d_in[3], (const float*)d_in[4], (const float*)d_in[5],
      (const float*)d_in[6], (const float*)d_in[7], (const float*)d_in[8],
      (const float*)d_in[9], (const float*)d_in[10],
      (float*)d_out);
}

// Round 9
// 168.533 us; speedup vs baseline: 6.7060x; 6.7060x over previous
//
#include <hip/hip_runtime.h>

#define NBLK 256
#define NITER 32
#define ROWS 32
#define BH 33554432   // B*H

typedef __attribute__((ext_vector_type(8))) short bf16x8;
typedef __attribute__((ext_vector_type(4))) float f32x4;

__device__ __forceinline__ unsigned short f2bf(float f) {
  unsigned int u = __float_as_uint(f);
  u += 0x7fffu + ((u >> 16) & 1u);  // round-to-nearest-even
  return (unsigned short)(u >> 16);
}

__device__ __forceinline__ float fexp(float x) { return __builtin_amdgcn_exp2f(x * 1.44269504f); }
__device__ __forceinline__ float sigm(float x) { return __builtin_amdgcn_rcpf(1.f + fexp(-x)); }
__device__ __forceinline__ float ftanh(float x) { return 1.f - 2.f * __builtin_amdgcn_rcpf(1.f + fexp(2.f * x)); }

// Async staging: X/H go straight to LDS as fp32 via global_load_lds (zero VGPR
// staging, in flight across the whole compute window). LDS layout is linear
// rows of 256 f32 (1KB) with a 3-bit XOR chunk swizzle applied on BOTH sides
// (pre-swizzled global source + swizzled ds_read) per the both-sides rule.
// Weights resident in reg/AGPR frags (r5/r7-verified layout, mfma(wf, b)).
#define GLOAD_LDS(G, L) __builtin_amdgcn_global_load_lds(                 \
    (const __attribute__((address_space(1))) unsigned int*)(G),           \
    (__attribute__((address_space(3))) unsigned int*)(L), 16, 0, 0)

__global__ __launch_bounds__(512, 2) void lstm_fused(
    const float* __restrict__ X, const float* __restrict__ H0, const float* __restrict__ C0,
    const float* __restrict__ Wii, const float* __restrict__ Whi,
    const float* __restrict__ Wif, const float* __restrict__ Whf,
    const float* __restrict__ Wio, const float* __restrict__ Who,
    const float* __restrict__ Wig, const float* __restrict__ Whg,
    float* __restrict__ Out) {
  __shared__ __align__(16) float Buf[2][ROWS * 256];  // 2 x 32KB fp32

  const int tid = threadIdx.x;
  const int wid = tid >> 6;
  const int lane = tid & 63;
  const int lrow = lane & 15;      // batch row within 16-row MFMA tile
  const int lkq = lane >> 4;       // k-quarter / output col-quarter
  const int s = lrow & 7;          // read-side XOR key (row mod 8)
  const int colw = wid * 16;       // wave's 16 output cols

  const int row_base = blockIdx.x * (NITER * ROWS);  // 1024 rows per block

  const float* Wxp[4] = {Wii, Wif, Wio, Wig};
  const float* Whp[4] = {Whi, Whf, Who, Whg};

  // ---- issue tile 0's async staging FIRST (overlaps the weight prologue) ----
#define GLDS_TILE(ROW0, BUFP) do {                                        \
    _Pragma("unroll")                                                     \
    for (int j_ = 0; j_ < 4; ++j_) {                                      \
      const int q_ = wid * 4 + j_;            /* local row 0..31 */       \
      const int cs_ = lane ^ (q_ & 7);        /* pre-swizzled src chunk */ \
      const float* g_ = (cs_ < 32)                                        \
          ? (X + (size_t)((ROW0) + q_) * 128 + cs_ * 4)                   \
          : (H0 + (size_t)((ROW0) + q_) * 128 + (cs_ - 32) * 4);          \
      GLOAD_LDS(g_, (BUFP) + q_ * 256);       /* wave-uniform dest */     \
    }                                                                     \
  } while (0)

  GLDS_TILE(row_base, &Buf[0][0]);

  // ---- weight fragments: 4 gates x 8 K-tiles (r7-verified A-operand map) ----
  bf16x8 wf[4][8];
#pragma unroll
  for (int g = 0; g < 4; ++g) {
#pragma unroll
    for (int kk = 0; kk < 8; ++kk) {
      const int k = kk * 32 + lkq * 8;
      const float* src = (kk < 4) ? (Wxp[g] + (size_t)(colw + lrow) * 128 + k)
                                  : (Whp[g] + (size_t)(colw + lrow) * 128 + (k - 128));
      float4 lo = *(const float4*)src;
      float4 hi = *(const float4*)(src + 4);
      bf16x8 w;
      w[0] = (short)f2bf(lo.x); w[1] = (short)f2bf(lo.y);
      w[2] = (short)f2bf(lo.z); w[3] = (short)f2bf(lo.w);
      w[4] = (short)f2bf(hi.x); w[5] = (short)f2bf(hi.y);
      w[6] = (short)f2bf(hi.z); w[7] = (short)f2bf(hi.w);
      wf[g][kk] = w;
    }
  }
  __syncthreads();  // tile 0 staged

  // One 16-row M-tile: read swizzled fp32 frags, cvt in-reg, 32 MFMA, epilogue.
#define MT(MT_, CV, CUR, ROW0) do {                                       \
    f32x4 a0 = {0.f, 0.f, 0.f, 0.f}, a1 = a0, a2 = a0, a3 = a0;           \
    const float* bp_ = (CUR) + ((MT_)*16 + lrow) * 256;                   \
    const int o0_ = ((lkq * 2) ^ s) * 4;                                  \
    const int o1_ = o0_ ^ 4;                                              \
    _Pragma("unroll")                                                     \
    for (int kk = 0; kk < 8; ++kk) {                                      \
      f32x4 u_ = *(const f32x4*)(bp_ + kk * 32 + o0_);                    \
      f32x4 v_ = *(const f32x4*)(bp_ + kk * 32 + o1_);                    \
      bf16x8 b_;                                                          \
      b_[0] = (short)f2bf(u_[0]); b_[1] = (short)f2bf(u_[1]);             \
      b_[2] = (short)f2bf(u_[2]); b_[3] = (short)f2bf(u_[3]);             \
      b_[4] = (short)f2bf(v_[0]); b_[5] = (short)f2bf(v_[1]);             \
      b_[6] = (short)f2bf(v_[2]); b_[7] = (short)f2bf(v_[3]);             \
      a0 = __builtin_amdgcn_mfma_f32_16x16x32_bf16(wf[0][kk], b_, a0, 0, 0, 0); \
      a1 = __builtin_amdgcn_mfma_f32_16x16x32_bf16(wf[1][kk], b_, a1, 0, 0, 0); \
      a2 = __builtin_amdgcn_mfma_f32_16x16x32_bf16(wf[2][kk], b_, a2, 0, 0, 0); \
      a3 = __builtin_amdgcn_mfma_f32_16x16x32_bf16(wf[3][kk], b_, a3, 0, 0, 0); \
    }                                                                     \
    f32x4 hv_, cf_;                                                       \
    _Pragma("unroll")                                                     \
    for (int j_ = 0; j_ < 4; ++j_) {                                      \
      const float itv = sigm(a0[j_]);                                     \
      const float ftv = sigm(a1[j_]);                                     \
      const float otv = sigm(a2[j_]);                                     \
      const float gtv = ftanh(a3[j_]);                                    \
      const float ctv = ftv * (CV)[j_] + itv * gtv;                       \
      cf_[j_] = ctv;                                                      \
      hv_[j_] = otv * ftanh(ctv);                                         \
    }                                                                     \
    const size_t ob_ = (size_t)((ROW0) + (MT_)*16 + lrow) * 128 + colw + lkq * 4; \
    *(f32x4*)(Out + ob_) = hv_;                                           \
    *(f32x4*)(Out + BH + ob_) = cf_;                                      \
  } while (0)

#define ITER(T, CUR, NXT) do {                                            \
    const int row0_ = row_base + (T) * ROWS;                              \
    /* cv first (oldest in vmcnt FIFO: epilogue's wait keeps gl_lds in */ \
    /* flight), then next tile's async staging */                         \
    f32x4 cva_ = *(const f32x4*)(C0 + (size_t)(row0_ + lrow) * 128 + colw + lkq * 4);      \
    f32x4 cvb_ = *(const f32x4*)(C0 + (size_t)(row0_ + 16 + lrow) * 128 + colw + lkq * 4); \
    if ((T) + 1 < NITER) GLDS_TILE(row0_ + ROWS, NXT);                    \
    MT(0, cva_, CUR, row0_);                                              \
    MT(1, cvb_, CUR, row0_);                                              \
    __syncthreads();  /* drains gl_lds(T+1); frees CUR for T+2 */         \
  } while (0)

  for (int t = 0; t < NITER; t += 2) {
    ITER(t, &Buf[0][0], &Buf[1][0]);
    ITER(t + 1, &Buf[1][0], &Buf[0][0]);
  }

#undef GLDS_TILE
#undef MT
#undef ITER
}

extern "C" void kernel_launch(void* const* d_in, const int* in_sizes, int n_in,
                              void* d_out, int out_size, void* d_ws, size_t ws_size,
                              hipStream_t stream) {
  (void)in_sizes; (void)n_in; (void)out_size; (void)d_ws; (void)ws_size;
  lstm_fused<<<NBLK, 512, 0, stream>>>(
      (const float*)d_in[0], (const float*)d_in[1], (const float*)d_in[2],
      (const float*)d_in[3], (const float*)d_in[4], (const float*)d_in[5],
      (const float*)d_in[6], (const float*)d_in[7], (const float*)d_in[8],
      (const float*)d_in[9], (const float*)d_in[10],
      (float*)d_out);
}